// Round 1
// 624.359 us; speedup vs baseline: 1.0351x; 1.0351x over previous
//
#include <hip/hip_runtime.h>

// Upsample 2x (zero-interleave + [1,3,3,1]^2/16 blur) == separable 2-tap blend:
//   out[2i]   = 0.25*x[i-1] + 0.75*x[i]
//   out[2i+1] = 0.75*x[i]   + 0.25*x[i+1]     (zero padding at edges)
// per dimension. Input (16,128,128,128) fp32 -> output (16,128,256,256) fp32.
//
// Row-streaming design: one wave owns a CH-row chunk of one (n,c) plane.
// Lane l holds input cols {2l, 2l+1} (float2). Walk rows downward carrying
// the column-interpolated previous row h[i-1] in registers:
//   - each input row is loaded exactly ONCE (vs 3x in the old kernel)
//   - column halo (cols 2l-1, 2l+2) comes from 2 shuffles, not scalar loads
//   - each step emits output rows 2i-1 and 2i as two contiguous 1 KiB
//     wave-stores (float4/lane).
// Per 64 B of output: 1 load + 2 stores + ~30 VALU (old: 22 mem ops + ~180).

#define H  128
#define W  128
#define OW 256
#define CH 32   // input rows per wave-chunk; 4 chunks cover a plane

__global__ __launch_bounds__(256) void upsample2x_kernel(
    const float* __restrict__ x, float* __restrict__ out)
{
    const int lane = threadIdx.x;               // 0..63: cols 2l, 2l+1
    const int s    = (int)threadIdx.y * CH;     // chunk start input row
    const int p    = blockIdx.x;                // plane = n*C + c, 0..2047

    const float* __restrict__ in = x + (size_t)p * (H * W) + (lane << 1);
    float*       __restrict__ o  = out + (size_t)p * (OW * OW) + (lane << 2);

    // Column zero-padding: fold the boundary into the 0.25 weight.
    const float wl = (lane == 0)  ? 0.0f : 0.25f;   // col -1
    const float wr = (lane == 63) ? 0.0f : 0.25f;   // col W

    // Column interpolation of one input row (float2 per lane) -> 4 out cols.
#define HROW(dst, m)                                         \
    {                                                        \
        float a0 = __shfl_up((m).y, 1);   /* col 2l-1 */     \
        float a3 = __shfl_down((m).x, 1); /* col 2l+2 */     \
        (dst).x = wl * a0 + 0.75f * (m).x;                   \
        (dst).y = 0.75f * (m).x + 0.25f * (m).y;             \
        (dst).z = 0.25f * (m).x + 0.75f * (m).y;             \
        (dst).w = 0.75f * (m).y + wr * a3;                   \
    }

    const float* rp   = in + s * W;
    float*       orow = o + (size_t)(2 * s) * OW;

    // h(row s-1): chunk halo (zero row above the plane)
    float4 hp;
    if (s > 0) {
        float2 m = *(const float2*)(rp - W);
        HROW(hp, m);
    } else {
        hp = make_float4(0.0f, 0.0f, 0.0f, 0.0f);
    }

    float2 mc = *(const float2*)rp;          // row s
    float2 mn = *(const float2*)(rp + W);    // row s+1 (CH >= 2, always valid)
    rp += 2 * W;

    // ---- peeled i = s: emit even output row 2s only ----
    {
        float4 hc;
        HROW(hc, mc);
        float4 ve;
        ve.x = 0.25f * hp.x + 0.75f * hc.x;
        ve.y = 0.25f * hp.y + 0.75f * hc.y;
        ve.z = 0.25f * hp.z + 0.75f * hc.z;
        ve.w = 0.25f * hp.w + 0.75f * hc.w;
        *(float4*)orow = ve;
        hp = hc;
        mc = mn;
        orow += 2 * OW;
    }

    // ---- main stream: i = s+1 .. s+CH-1, emit rows 2i-1 and 2i ----
    #pragma unroll 4
    for (int i = s + 1; i < s + CH; ++i) {
        float2 nx;                            // prefetch row i+1
        if (i < H - 1) nx = *(const float2*)rp;
        else           nx = make_float2(0.0f, 0.0f);  // zero row below plane
        rp += W;

        float4 hc;
        HROW(hc, mc);

        float4 vo, ve;
        vo.x = 0.75f * hp.x + 0.25f * hc.x;   // out row 2i-1
        vo.y = 0.75f * hp.y + 0.25f * hc.y;
        vo.z = 0.75f * hp.z + 0.25f * hc.z;
        vo.w = 0.75f * hp.w + 0.25f * hc.w;
        ve.x = 0.25f * hp.x + 0.75f * hc.x;   // out row 2i
        ve.y = 0.25f * hp.y + 0.75f * hc.y;
        ve.z = 0.25f * hp.z + 0.75f * hc.z;
        ve.w = 0.25f * hp.w + 0.75f * hc.w;
        *(float4*)(orow - OW) = vo;
        *(float4*)(orow)      = ve;

        hp = hc;
        mc = nx;
        orow += 2 * OW;
    }

    // ---- epilogue: odd output row 2(s+CH)-1; mc = row s+CH (or zeros) ----
    {
        float4 hc;
        HROW(hc, mc);
        float4 vo;
        vo.x = 0.75f * hp.x + 0.25f * hc.x;
        vo.y = 0.75f * hp.y + 0.25f * hc.y;
        vo.z = 0.75f * hp.z + 0.25f * hc.z;
        vo.w = 0.75f * hp.w + 0.25f * hc.w;
        *(float4*)(orow - OW) = vo;
    }
#undef HROW
}

extern "C" void kernel_launch(void* const* d_in, const int* in_sizes, int n_in,
                              void* d_out, int out_size, void* d_ws, size_t ws_size,
                              hipStream_t stream)
{
    const float* x = (const float*)d_in[0];
    // d_in[1] is the 4x4 kernel; values fixed by construction, baked in above.
    float* out = (float*)d_out;

    dim3 block(64, 4, 1);      // 4 waves = 4 row-chunks of one plane
    dim3 grid(16 * 128, 1, 1); // one block per (n,c) plane; 2048 blocks
    upsample2x_kernel<<<grid, block, 0, stream>>>(x, out);
}